// Round 11
// baseline (138.103 us; speedup 1.0000x reference)
//
#include <hip/hip_runtime.h>

#define NROIS 1024
#define BANDS 7
#define M_TOT (NROIS*BANDS)        // 7168
#define ROI_W 224
#define BAND_H 16
#define FLATD 512
#define HD 1024                     // 8 heads * 128
#define PROV 38
#define ALPHA 25
#define ADC 35
#define NAD 6

#define OFF_A     (M_TOT*PROV)               // 272384
#define OFF_AD    (OFF_A + M_TOT*ALPHA)      // 451584
#define OFF_MASK  (OFF_AD + NAD*M_TOT*ADC)   // 1956864
#define OFF_TOTAL (OFF_MASK + M_TOT)         // 1964032

typedef __attribute__((ext_vector_type(4))) float f32x4;
typedef __attribute__((ext_vector_type(2))) float f32x2;
typedef __attribute__((ext_vector_type(8))) short bf16x8;

static __device__ __forceinline__ unsigned short f2bf(float f){
    union { float f; unsigned int u; } v; v.f = f;
    unsigned int u = v.u;
    unsigned int r = (u + 0x7fffu + ((u >> 16) & 1u)) >> 16;
    return (unsigned short)r;
}

// async global->LDS, 16B per lane, wave-uniform LDS base + lane*16
#define GL16(gp, lp) __builtin_amdgcn_global_load_lds( \
    (const __attribute__((address_space(1))) unsigned int*)(gp), \
    (__attribute__((address_space(3))) unsigned int*)(lp), 16, 0, 0)

// P2[c][row][s][q] = max over x[c][row..row+1][(14q+s)..(14q+s+13)]
#define P2ROW(c,row) (((size_t)((c)*1023 + (row)))*1022)

// ---------------- Kernel 0: fused precompute P2 (s-pair sliding max) + weight conversions
__global__ __launch_bounds__(256) void k_pre_cvt(
    const float* __restrict__ x, const float* __restrict__ w1,
    const float* __restrict__ w2p, const float* __restrict__ b2p,
    const float* __restrict__ w2a, const float* __restrict__ b2a,
    const float* __restrict__ w2ad, const float* __restrict__ b2ad,
    float* __restrict__ P, unsigned short* __restrict__ Bt,
    unsigned short* __restrict__ B2, float* __restrict__ bias2)
{
    __shared__ float v[1024];
    int blk = blockIdx.x;
    int t = threadIdx.x;
    if (blk < 3069){
        int c = blk / 1023, r = blk - c*1023;
        const float* row0 = x + ((size_t)c*1024 + r)*1024;
        const float* row1 = row0 + 1024;
        #pragma unroll
        for (int i=0;i<4;i++){
            int j = t + i*256;
            v[j] = fmaxf(row0[j], row1[j]);
        }
        __syncthreads();
        float* Pr = P + P2ROW(c, r);
        // s-pair: outputs (s,q) and (s+1,q) share 13-wide core max
        #pragma unroll
        for (int ii=0; ii<2; ii++){
            int i = t + ii*256;
            if (i < 511){                      // 7 s2-groups x 73 q
                int s2 = i / 73, q = i - s2*73;
                int s = 2*s2;
                int j = 14*q + s;
                if (j < 1011){
                    float core = v[j+1];
                    #pragma unroll
                    for (int d=2; d<14; d++) core = fmaxf(core, v[j+d]);
                    Pr[s*73 + q] = fmaxf(core, v[j]);
                    if (j+1 < 1011)
                        Pr[(s+1)*73 + q] = fmaxf(core, v[j+14]);
                }
            }
        }
    } else {
        int i = (blk - 3069)*256 + t;
        if (i < 524288){
            int k = i >> 10, n = i & 1023;
            float val = w1[((size_t)(n>>7)*512 + k)*128 + (n&127)];
            Bt[(size_t)n*512 + k] = f2bf(val);
        } else {
            int j = i - 524288;          // < 49152
            int h = j / 6144;
            int rem = j - h*6144;
            int n = rem >> 7, k = rem & 127;
            float val = 0.f;
            if (h == 0){ if (n < 38) val = w2p[k*38 + n]; }
            else if (h == 1){ if (n < 25) val = w2a[k*25 + n]; }
            else { if (n < 35) val = w2ad[(size_t)(h-2)*128*35 + k*35 + n]; }
            B2[j] = f2bf(val);
            if (j < 8*48){
                int hh = j / 48, nn = j - hh*48;
                float bv = 0.f;
                if (hh == 0){ if (nn < 38) bv = b2p[nn]; }
                else if (hh == 1){ if (nn < 25) bv = b2a[nn]; }
                else { if (nn < 35) bv = b2ad[(hh-2)*35 + nn]; }
                bias2[j] = bv;
            }
        }
    }
}

// ---------------- Kernel 1: per-ROI block; ALL 7 bands gathered in one burst; conv from read-only LDS.
__global__ __launch_bounds__(256) void k_extract(
    const float* __restrict__ P, const int* __restrict__ rois,
    const float* __restrict__ conv_w, const float* __restrict__ conv_b,
    unsigned short* __restrict__ flat)
{
    __shared__ float pl[3][BANDS][10][20];   // 16800 B, zero borders per band
    __shared__ float cw[432];
    __shared__ float cb[16];

    int r = blockIdx.x;
    int t = threadIdx.x;
    int xx = rois[r*4+0];
    int y1 = rois[r*4+1];
    int sx = xx % 14, qx = xx / 14;
    int o2 = t >> 5, p = (t >> 3) & 3, q = t & 7;

    for (int i=t;i<432;i+=256) cw[i]=conv_w[i];
    if (t<16) cb[t]=conv_b[t];
    for (int i=t;i<3*BANDS*10*20;i+=256) ((float*)pl)[i]=0.f;
    __syncthreads();

    // single burst gather of all bands: 2688 values, coalesced 64B segments
    for (int idx=t; idx<3*BANDS*8*16; idx+=256){
        int pw = idx & 15;
        int rem = idx >> 4;          // c*56 + b*8 + ph
        int ph = rem & 7;
        int bb = (rem >> 3) % BANDS;
        int c  = rem / (8*BANDS);
        pl[c][bb][ph+1][pw+1] = P[P2ROW(c, y1 + bb*BAND_H + 2*ph) + (size_t)sx*73 + qx + pw];
    }
    __syncthreads();

    // weights in registers (channels o2 and o2+8)
    float w[2][27];
    #pragma unroll
    for (int oi=0;oi<2;oi++)
      #pragma unroll
      for (int k=0;k<27;k++) w[oi][k] = cw[(o2 + oi*8)*27 + k];
    float bias0 = cb[o2], bias1 = cb[o2+8];

    for (int b=0; b<BANDS; b++){
        float s0[4] = {bias0,bias0,bias0,bias0};
        float s1[4] = {bias1,bias1,bias1,bias1};
        #pragma unroll
        for (int c=0;c<3;c++){
            float pt[4][4];
            #pragma unroll
            for (int di=0; di<4; di++){
                f32x2 a  = *(const f32x2*)&pl[c][b][2*p+di][2*q];
                f32x2 bb2 = *(const f32x2*)&pl[c][b][2*p+di][2*q+2];
                pt[di][0]=a.x; pt[di][1]=a.y; pt[di][2]=bb2.x; pt[di][3]=bb2.y;
            }
            #pragma unroll
            for (int kh=0;kh<3;kh++)
              #pragma unroll
              for (int kw=0;kw<3;kw++){
                float w0 = w[0][c*9+kh*3+kw];
                float w1v = w[1][c*9+kh*3+kw];
                #pragma unroll
                for (int pos=0;pos<4;pos++){
                    float pv = pt[kh + (pos>>1)][kw + (pos&1)];
                    s0[pos] += pv*w0;
                    s1[pos] += pv*w1v;
                }
              }
        }
        float mx0 = fmaxf(fmaxf(fmaxf(s0[0],s0[1]), fmaxf(s0[2],s0[3])), 0.f);
        float mx1 = fmaxf(fmaxf(fmaxf(s1[0],s1[1]), fmaxf(s1[2],s1[3])), 0.f);
        size_t base = ((size_t)r*BANDS + b)*512;
        flat[base + t]       = f2bf(mx0);
        flat[base + t + 256] = f2bf(mx1);
    }
}

// ---------------- Kernel 2: fused fc1 + heads + per-row LSE
// 3-buffer counted-vmcnt pipeline (T3/T4), source-swizzled staging (rule 21).
__global__ __launch_bounds__(256) void k_fc1_heads(
    const unsigned short* __restrict__ A, const unsigned short* __restrict__ Bt,
    const float* __restrict__ b1, const unsigned short* __restrict__ B2,
    const float* __restrict__ bias2, float* __restrict__ out,
    float* __restrict__ lse_ws)
{
    __shared__ short smem[24576];              // 49152B: As[3][4096], Bs[3][4096]; Hl union (16896)
    short* As = smem;
    short* Bs = smem + 12288;
    short* Hl = smem;

    int bm = blockIdx.x, h = blockIdx.y;
    int m0 = bm*128;
    int t = threadIdx.x;
    int wid = t >> 6, lane = t & 63;
    int wr = wid >> 1, wc = wid & 1;
    int l15 = lane & 15, l4 = lane >> 4;

    if (bm == 0 && h == 0 && t == 0) out[OFF_TOTAL] = 0.f;

    // source-side XOR swizzle: lane loads global chunk (lane&3)^(row&3); LDS stays linear.
    int lrow = lane >> 2;
    int lch  = (lane & 3) ^ (lrow & 3);
    const unsigned short* gA = A  + ((size_t)(m0    + wid*16 + lrow))*FLATD + lch*8;
    const unsigned short* gB = Bt + ((size_t)(h*128 + wid*16 + lrow))*FLATD + lch*8;

    f32x4 acc[4][4];
    #pragma unroll
    for (int i=0;i<4;i++)
      #pragma unroll
      for (int j=0;j<4;j++) acc[i][j] = (f32x4){0.f,0.f,0.f,0.f};

#define STAGE(ks, buf) do { int _k0 = (ks)*32; \
    GL16(gA + _k0,            As + (buf)*4096 + wid*512); \
    GL16(gA + 64*FLATD + _k0, As + (buf)*4096 + 2048 + wid*512); \
    GL16(gB + _k0,            Bs + (buf)*4096 + wid*512); \
    GL16(gB + 64*FLATD + _k0, Bs + (buf)*4096 + 2048 + wid*512); } while(0)

    STAGE(0, 0);
    STAGE(1, 1);

    #pragma unroll
    for (int ks=0; ks<16; ks++){
        if (ks < 14) STAGE(ks+2, (ks+2)%3);
        if (ks < 14)       asm volatile("s_waitcnt vmcnt(8)" ::: "memory");
        else if (ks == 14) asm volatile("s_waitcnt vmcnt(4)" ::: "memory");
        else               asm volatile("s_waitcnt vmcnt(0)" ::: "memory");
        __builtin_amdgcn_s_barrier();
        __builtin_amdgcn_sched_barrier(0);
        int cur = ks % 3;
        bf16x8 af[4], bfv[4];
        #pragma unroll
        for (int mf=0;mf<4;mf++){
            int row = wr*64 + mf*16 + l15;
            af[mf]  = *(const bf16x8*)&As[cur*4096 + row*32 + ((l4 ^ (l15&3))*8)];
        }
        #pragma unroll
        for (int nf=0;nf<4;nf++){
            int row = wc*64 + nf*16 + l15;
            bfv[nf] = *(const bf16x8*)&Bs[cur*4096 + row*32 + ((l4 ^ (l15&3))*8)];
        }
        #pragma unroll
        for (int mf=0;mf<4;mf++)
          #pragma unroll
          for (int nf=0;nf<4;nf++)
            acc[mf][nf] = __builtin_amdgcn_mfma_f32_16x16x32_bf16(af[mf], bfv[nf], acc[mf][nf], 0, 0, 0);
        __builtin_amdgcn_sched_barrier(0);
        __builtin_amdgcn_s_barrier();
    }
#undef STAGE

    __syncthreads();

    // Phase 2a: H tile -> LDS (bf16, bias+relu applied)
    #pragma unroll
    for (int nf=0;nf<4;nf++){
        int col = wc*64 + nf*16 + l15;
        float bias = b1[h*128 + col];
        #pragma unroll
        for (int mf=0;mf<4;mf++){
            #pragma unroll
            for (int reg=0;reg<4;reg++){
                int row = wr*64 + mf*16 + l4*4 + reg;
                Hl[row*132 + col] = (short)f2bf(fmaxf(acc[mf][nf][reg] + bias, 0.f));
            }
        }
    }
    __syncthreads();

    // Phase 2b: logits = H_tile @ W2[head]
    f32x4 acc2[2][3];
    #pragma unroll
    for (int i=0;i<2;i++)
      #pragma unroll
      for (int j=0;j<3;j++) acc2[i][j] = (f32x4){0.f,0.f,0.f,0.f};

    const unsigned short* Bh = B2 + (size_t)h*6144;
    #pragma unroll
    for (int ks=0; ks<4; ks++){
        bf16x8 ha[2], hb[3];
        #pragma unroll
        for (int m2=0;m2<2;m2++)
            ha[m2] = *(const bf16x8*)&Hl[(wid*32 + m2*16 + l15)*132 + ks*32 + l4*8];
        #pragma unroll
        for (int nf=0;nf<3;nf++)
            hb[nf] = *(const bf16x8*)(Bh + (nf*16 + l15)*128 + ks*32 + l4*8);
        #pragma unroll
        for (int m2=0;m2<2;m2++)
          #pragma unroll
          for (int nf=0;nf<3;nf++)
            acc2[m2][nf] = __builtin_amdgcn_mfma_f32_16x16x32_bf16(ha[m2], hb[nf], acc2[m2][nf], 0, 0, 0);
    }

    int Nh = (h==0) ? 38 : ((h==1) ? 25 : 35);
    #pragma unroll
    for (int nf=0;nf<3;nf++){
        int col = nf*16 + l15;
        float bv = bias2[h*48 + col];
        #pragma unroll
        for (int m2=0;m2<2;m2++){
            #pragma unroll
            for (int reg=0;reg<4;reg++){
                acc2[m2][nf][reg] += bv;
                if (col < Nh){
                    int m = m0 + wid*32 + m2*16 + l4*4 + reg;
                    size_t a;
                    if (h == 0)      a = (size_t)m*38 + col;
                    else if (h == 1) a = OFF_A + (size_t)m*25 + col;
                    else             a = OFF_AD + ((size_t)(h-2)*M_TOT + m)*35 + col;
                    out[a] = acc2[m2][nf][reg];
                }
            }
        }
    }

    // Phase 2c: per-row LSE via 16-lane shfl reduce
    #pragma unroll
    for (int m2=0;m2<2;m2++){
        #pragma unroll
        for (int reg=0;reg<4;reg++){
            float mx = -1e30f;
            #pragma unroll
            for (int nf=0;nf<3;nf++){
                int col = nf*16 + l15;
                if (col < Nh) mx = fmaxf(mx, acc2[m2][nf][reg]);
            }
            #pragma unroll
            for (int d=1; d<16; d<<=1) mx = fmaxf(mx, __shfl_xor(mx, d));
            float s = 0.f;
            #pragma unroll
            for (int nf=0;nf<3;nf++){
                int col = nf*16 + l15;
                if (col < Nh) s += __expf(acc2[m2][nf][reg] - mx);
            }
            #pragma unroll
            for (int d=1; d<16; d<<=1) s += __shfl_xor(s, d);
            if (l15 == 0){
                int m = m0 + wid*32 + m2*16 + l4*4 + reg;
                lse_ws[(size_t)m*8 + h] = mx + __logf(s);
            }
        }
    }
}

// ---------------- Kernel 3: per-row losses + mask + total
__global__ __launch_bounds__(64) void k_loss(
    const float* __restrict__ lse_ws, const int* __restrict__ det_t,
    const int* __restrict__ cls_t, float* __restrict__ out)
{
    int m = blockIdx.x*64 + threadIdx.x;
    if (m >= M_TOT) return;
    int r = m / 7;
    const float* L = lse_ws + (size_t)m*8;
    float det_loss = L[0] - out[(size_t)m*38 + det_t[r]];
    bool mk = det_loss < 0.25f;
    out[OFF_MASK + m] = mk ? 1.f : 0.f;
    if (mk){
        const int* ct = cls_t + r*8;
        float c = (L[0] - out[(size_t)m*38 + ct[0]]) + (L[1] - out[OFF_A + (size_t)m*25 + ct[1]]);
        #pragma unroll
        for (int j=0;j<6;j++)
            c += L[2+j] - out[OFF_AD + ((size_t)j*M_TOT + m)*35 + ct[2+j]];
        atomicAdd(out + OFF_TOTAL, c);
    }
}

extern "C" void kernel_launch(void* const* d_in, const int* in_sizes, int n_in,
                              void* d_out, int out_size, void* d_ws, size_t ws_size,
                              hipStream_t stream) {
    const float* x      = (const float*)d_in[0];
    const int*   rois   = (const int*)d_in[1];
    const int*   det    = (const int*)d_in[2];
    const int*   cls    = (const int*)d_in[3];
    const float* conv_w = (const float*)d_in[4];
    const float* conv_b = (const float*)d_in[5];
    const float* w1     = (const float*)d_in[6];
    const float* b1     = (const float*)d_in[7];
    const float* w2p    = (const float*)d_in[8];
    const float* b2p    = (const float*)d_in[9];
    const float* w2a    = (const float*)d_in[10];
    const float* b2a    = (const float*)d_in[11];
    const float* w2ad   = (const float*)d_in[12];
    const float* b2ad   = (const float*)d_in[13];
    float* out = (float*)d_out;

    char* w = (char*)d_ws;
    unsigned short* flatbf = (unsigned short*)w;                    // 7,340,032 B
    unsigned short* BtW    = (unsigned short*)(w + 7340032);        // 1,048,576 B
    unsigned short* B2     = (unsigned short*)(w + 8388608);        //    98,304 B
    float*  bias2          = (float*)(w + 8486912);                 //     1,536 B
    float*  lse            = (float*)(w + 8488448);                 //   229,376 B
    float*  P              = (float*)(w + 8717824);                 // 12,546,072 B

    k_pre_cvt<<<3069 + 2240, 256, 0, stream>>>(x, w1, w2p, b2p, w2a, b2a, w2ad, b2ad,
                                               P, BtW, B2, bias2);
    k_extract<<<NROIS, 256, 0, stream>>>(P, rois, conv_w, conv_b, flatbf);
    k_fc1_heads<<<dim3(56, 8), 256, 0, stream>>>(flatbf, BtW, b1, B2, bias2, out, lse);
    k_loss<<<112, 64, 0, stream>>>(lse, det, cls, out);
}

// Round 12
// 137.044 us; speedup vs baseline: 1.0077x; 1.0077x over previous
//
#include <hip/hip_runtime.h>

#define NROIS 1024
#define BANDS 7
#define M_TOT (NROIS*BANDS)        // 7168
#define ROI_W 224
#define BAND_H 16
#define FLATD 512
#define HD 1024                     // 8 heads * 128
#define PROV 38
#define ALPHA 25
#define ADC 35
#define NAD 6

#define OFF_A     (M_TOT*PROV)               // 272384
#define OFF_AD    (OFF_A + M_TOT*ALPHA)      // 451584
#define OFF_MASK  (OFF_AD + NAD*M_TOT*ADC)   // 1956864
#define OFF_TOTAL (OFF_MASK + M_TOT)         // 1964032

typedef __attribute__((ext_vector_type(4))) float f32x4;
typedef __attribute__((ext_vector_type(2))) float f32x2;
typedef __attribute__((ext_vector_type(8))) short bf16x8;

static __device__ __forceinline__ unsigned short f2bf(float f){
    union { float f; unsigned int u; } v; v.f = f;
    unsigned int u = v.u;
    unsigned int r = (u + 0x7fffu + ((u >> 16) & 1u)) >> 16;
    return (unsigned short)r;
}

// async global->LDS, 16B per lane, wave-uniform LDS base + lane*16
#define GL16(gp, lp) __builtin_amdgcn_global_load_lds( \
    (const __attribute__((address_space(1))) unsigned int*)(gp), \
    (__attribute__((address_space(3))) unsigned int*)(lp), 16, 0, 0)

// P2[c][row][s][q] = max over x[c][row..row+1][(14q+s)..(14q+s+13)]
#define P2ROW(c,row) (((size_t)((c)*1023 + (row)))*1022)

// ---------------- Kernel 0: fused precompute P2 + w1 LDS-transpose cvt + head-weight cvt
__global__ __launch_bounds__(256) void k_pre_cvt(
    const float* __restrict__ x, const float* __restrict__ w1,
    const float* __restrict__ w2p, const float* __restrict__ b2p,
    const float* __restrict__ w2a, const float* __restrict__ b2a,
    const float* __restrict__ w2ad, const float* __restrict__ b2ad,
    float* __restrict__ P, unsigned short* __restrict__ Bt,
    unsigned short* __restrict__ B2, float* __restrict__ bias2)
{
    __shared__ float sm[64*65];     // union: v[1024] (P part) / ts[64][65] (transpose part)
    int blk = blockIdx.x;
    int t = threadIdx.x;
    if (blk < 3069){
        float* v = sm;
        int c = blk / 1023, r = blk - c*1023;
        const float* row0 = x + ((size_t)c*1024 + r)*1024;
        const float* row1 = row0 + 1024;
        #pragma unroll
        for (int i=0;i<4;i++){
            int j = t + i*256;
            v[j] = fmaxf(row0[j], row1[j]);
        }
        __syncthreads();
        float* Pr = P + P2ROW(c, r);
        #pragma unroll
        for (int ii=0; ii<2; ii++){
            int i = t + ii*256;
            if (i < 511){                      // 7 s2-groups x 73 q
                int s2 = i / 73, q = i - s2*73;
                int s = 2*s2;
                int j = 14*q + s;
                if (j < 1011){
                    float core = v[j+1];
                    #pragma unroll
                    for (int d=2; d<14; d++) core = fmaxf(core, v[j+d]);
                    Pr[s*73 + q] = fmaxf(core, v[j]);
                    if (j+1 < 1011)
                        Pr[(s+1)*73 + q] = fmaxf(core, v[j+14]);
                }
            }
        }
    } else if (blk < 3197){
        // w1 (8,512,128) -> Bt[n][k] bf16, 64x64 tile transpose via LDS
        int tt = blk - 3069;                  // 0..127
        int h  = tt >> 4;
        int rem = tt & 15;
        int k0 = (rem >> 1) * 64;
        int n0 = (rem & 1) * 64;
        const float* W = w1 + (size_t)h*65536;
        #pragma unroll
        for (int e=0;e<16;e++){
            int idx = e*256 + t;
            int kk = idx >> 6, nn = idx & 63;
            sm[kk*65 + nn] = W[(size_t)(k0+kk)*128 + n0 + nn];   // coalesced 256B reads
        }
        __syncthreads();
        #pragma unroll
        for (int e=0;e<16;e++){
            int idx = e*256 + t;
            int nn = idx >> 6, kk = idx & 63;
            Bt[(size_t)(h*128 + n0 + nn)*512 + k0 + kk] = f2bf(sm[kk*65 + nn]);  // coalesced 128B writes
        }
    } else {
        int j = (blk - 3197)*256 + t;          // < 49152
        int h = j / 6144;
        int rem = j - h*6144;
        int n = rem >> 7, k = rem & 127;
        float val = 0.f;
        if (h == 0){ if (n < 38) val = w2p[k*38 + n]; }
        else if (h == 1){ if (n < 25) val = w2a[k*25 + n]; }
        else { if (n < 35) val = w2ad[(size_t)(h-2)*128*35 + k*35 + n]; }
        B2[j] = f2bf(val);
        if (j < 8*48){
            int hh = j / 48, nn = j - hh*48;
            float bv = 0.f;
            if (hh == 0){ if (nn < 38) bv = b2p[nn]; }
            else if (hh == 1){ if (nn < 25) bv = b2a[nn]; }
            else { if (nn < 35) bv = b2ad[(hh-2)*35 + nn]; }
            bias2[j] = bv;
        }
    }
}

// ---------------- Kernel 1: per-ROI block; all 7 bands gathered in one burst; conv from read-only LDS.
__global__ __launch_bounds__(256) void k_extract(
    const float* __restrict__ P, const int* __restrict__ rois,
    const float* __restrict__ conv_w, const float* __restrict__ conv_b,
    unsigned short* __restrict__ flat)
{
    __shared__ float pl[3][BANDS][10][20];   // 16800 B, zero borders per band
    __shared__ float cw[432];
    __shared__ float cb[16];

    int r = blockIdx.x;
    int t = threadIdx.x;
    int xx = rois[r*4+0];
    int y1 = rois[r*4+1];
    int sx = xx % 14, qx = xx / 14;
    int o2 = t >> 5, p = (t >> 3) & 3, q = t & 7;

    for (int i=t;i<432;i+=256) cw[i]=conv_w[i];
    if (t<16) cb[t]=conv_b[t];
    for (int i=t;i<3*BANDS*10*20;i+=256) ((float*)pl)[i]=0.f;
    __syncthreads();

    for (int idx=t; idx<3*BANDS*8*16; idx+=256){
        int pw = idx & 15;
        int rem = idx >> 4;          // c*56 + b*8 + ph
        int ph = rem & 7;
        int bb = (rem >> 3) % BANDS;
        int c  = rem / (8*BANDS);
        pl[c][bb][ph+1][pw+1] = P[P2ROW(c, y1 + bb*BAND_H + 2*ph) + (size_t)sx*73 + qx + pw];
    }
    __syncthreads();

    float w[2][27];
    #pragma unroll
    for (int oi=0;oi<2;oi++)
      #pragma unroll
      for (int k=0;k<27;k++) w[oi][k] = cw[(o2 + oi*8)*27 + k];
    float bias0 = cb[o2], bias1 = cb[o2+8];

    for (int b=0; b<BANDS; b++){
        float s0[4] = {bias0,bias0,bias0,bias0};
        float s1[4] = {bias1,bias1,bias1,bias1};
        #pragma unroll
        for (int c=0;c<3;c++){
            float pt[4][4];
            #pragma unroll
            for (int di=0; di<4; di++){
                f32x2 a   = *(const f32x2*)&pl[c][b][2*p+di][2*q];
                f32x2 bb2 = *(const f32x2*)&pl[c][b][2*p+di][2*q+2];
                pt[di][0]=a.x; pt[di][1]=a.y; pt[di][2]=bb2.x; pt[di][3]=bb2.y;
            }
            #pragma unroll
            for (int kh=0;kh<3;kh++)
              #pragma unroll
              for (int kw=0;kw<3;kw++){
                float w0 = w[0][c*9+kh*3+kw];
                float w1v = w[1][c*9+kh*3+kw];
                #pragma unroll
                for (int pos=0;pos<4;pos++){
                    float pv = pt[kh + (pos>>1)][kw + (pos&1)];
                    s0[pos] += pv*w0;
                    s1[pos] += pv*w1v;
                }
              }
        }
        float mx0 = fmaxf(fmaxf(fmaxf(s0[0],s0[1]), fmaxf(s0[2],s0[3])), 0.f);
        float mx1 = fmaxf(fmaxf(fmaxf(s1[0],s1[1]), fmaxf(s1[2],s1[3])), 0.f);
        size_t base = ((size_t)r*BANDS + b)*512;
        flat[base + t]       = f2bf(mx0);
        flat[base + t + 256] = f2bf(mx1);
    }
}

// ---------------- Kernel 2: fused fc1 + heads + per-row LSE  (R9 2-buffer structure)
__global__ __launch_bounds__(256) void k_fc1_heads(
    const unsigned short* __restrict__ A, const unsigned short* __restrict__ Bt,
    const float* __restrict__ b1, const unsigned short* __restrict__ B2,
    const float* __restrict__ bias2, float* __restrict__ out,
    float* __restrict__ lse_ws)
{
    __shared__ short smem[16896];              // union: staging (16384) / Hl (16896)
    short* As = smem;                          // As[2][4096]
    short* Bs = smem + 8192;                   // Bs[2][4096]
    short* Hl = smem;                          // Hl[128][132]

    int bm = blockIdx.x, h = blockIdx.y;
    int m0 = bm*128;
    int t = threadIdx.x;
    int wid = t >> 6, lane = t & 63;
    int wr = wid >> 1, wc = wid & 1;
    int l15 = lane & 15, l4 = lane >> 4;

    if (bm == 0 && h == 0 && t == 0) out[OFF_TOTAL] = 0.f;

    const unsigned short* gA = A  + ((size_t)(m0    + wid*16 + (lane>>2)))*FLATD + (lane&3)*8;
    const unsigned short* gB = Bt + ((size_t)(h*128 + wid*16 + (lane>>2)))*FLATD + (lane&3)*8;

    f32x4 acc[4][4];
    #pragma unroll
    for (int i=0;i<4;i++)
      #pragma unroll
      for (int j=0;j<4;j++) acc[i][j] = (f32x4){0.f,0.f,0.f,0.f};

    GL16(gA,            As + wid*512);
    GL16(gA + 64*FLATD, As + 2048 + wid*512);
    GL16(gB,            Bs + wid*512);
    GL16(gB + 64*FLATD, Bs + 2048 + wid*512);
    __syncthreads();

    #pragma unroll
    for (int ks=0; ks<16; ks++){
        int cur = ks & 1;
        if (ks < 15){
            int k1 = (ks+1)*32;
            int nb = (cur^1)*4096;
            GL16(gA + k1,            As + nb + wid*512);
            GL16(gA + 64*FLATD + k1, As + nb + 2048 + wid*512);
            GL16(gB + k1,            Bs + nb + wid*512);
            GL16(gB + 64*FLATD + k1, Bs + nb + 2048 + wid*512);
        }
        bf16x8 af[4], bfv[4];
        #pragma unroll
        for (int mf=0;mf<4;mf++) af[mf]  = *(const bf16x8*)&As[cur*4096 + (wr*64 + mf*16 + l15)*32 + l4*8];
        #pragma unroll
        for (int nf=0;nf<4;nf++) bfv[nf] = *(const bf16x8*)&Bs[cur*4096 + (wc*64 + nf*16 + l15)*32 + l4*8];
        #pragma unroll
        for (int mf=0;mf<4;mf++)
          #pragma unroll
          for (int nf=0;nf<4;nf++)
            acc[mf][nf] = __builtin_amdgcn_mfma_f32_16x16x32_bf16(af[mf], bfv[nf], acc[mf][nf], 0, 0, 0);
        __syncthreads();
    }

    // Phase 2a: H tile -> LDS (bf16, bias+relu applied)
    #pragma unroll
    for (int nf=0;nf<4;nf++){
        int col = wc*64 + nf*16 + l15;
        float bias = b1[h*128 + col];
        #pragma unroll
        for (int mf=0;mf<4;mf++){
            #pragma unroll
            for (int reg=0;reg<4;reg++){
                int row = wr*64 + mf*16 + l4*4 + reg;
                Hl[row*132 + col] = (short)f2bf(fmaxf(acc[mf][nf][reg] + bias, 0.f));
            }
        }
    }
    __syncthreads();

    // Phase 2b: logits = H_tile @ W2[head]
    f32x4 acc2[2][3];
    #pragma unroll
    for (int i=0;i<2;i++)
      #pragma unroll
      for (int j=0;j<3;j++) acc2[i][j] = (f32x4){0.f,0.f,0.f,0.f};

    const unsigned short* Bh = B2 + (size_t)h*6144;
    #pragma unroll
    for (int ks=0; ks<4; ks++){
        bf16x8 ha[2], hb[3];
        #pragma unroll
        for (int m2=0;m2<2;m2++)
            ha[m2] = *(const bf16x8*)&Hl[(wid*32 + m2*16 + l15)*132 + ks*32 + l4*8];
        #pragma unroll
        for (int nf=0;nf<3;nf++)
            hb[nf] = *(const bf16x8*)(Bh + (nf*16 + l15)*128 + ks*32 + l4*8);
        #pragma unroll
        for (int m2=0;m2<2;m2++)
          #pragma unroll
          for (int nf=0;nf<3;nf++)
            acc2[m2][nf] = __builtin_amdgcn_mfma_f32_16x16x32_bf16(ha[m2], hb[nf], acc2[m2][nf], 0, 0, 0);
    }

    int Nh = (h==0) ? 38 : ((h==1) ? 25 : 35);
    #pragma unroll
    for (int nf=0;nf<3;nf++){
        int col = nf*16 + l15;
        float bv = bias2[h*48 + col];
        #pragma unroll
        for (int m2=0;m2<2;m2++){
            #pragma unroll
            for (int reg=0;reg<4;reg++){
                acc2[m2][nf][reg] += bv;
                if (col < Nh){
                    int m = m0 + wid*32 + m2*16 + l4*4 + reg;
                    size_t a;
                    if (h == 0)      a = (size_t)m*38 + col;
                    else if (h == 1) a = OFF_A + (size_t)m*25 + col;
                    else             a = OFF_AD + ((size_t)(h-2)*M_TOT + m)*35 + col;
                    out[a] = acc2[m2][nf][reg];
                }
            }
        }
    }

    // Phase 2c: per-row LSE via 16-lane shfl reduce
    #pragma unroll
    for (int m2=0;m2<2;m2++){
        #pragma unroll
        for (int reg=0;reg<4;reg++){
            float mx = -1e30f;
            #pragma unroll
            for (int nf=0;nf<3;nf++){
                int col = nf*16 + l15;
                if (col < Nh) mx = fmaxf(mx, acc2[m2][nf][reg]);
            }
            #pragma unroll
            for (int d=1; d<16; d<<=1) mx = fmaxf(mx, __shfl_xor(mx, d));
            float s = 0.f;
            #pragma unroll
            for (int nf=0;nf<3;nf++){
                int col = nf*16 + l15;
                if (col < Nh) s += __expf(acc2[m2][nf][reg] - mx);
            }
            #pragma unroll
            for (int d=1; d<16; d<<=1) s += __shfl_xor(s, d);
            if (l15 == 0){
                int m = m0 + wid*32 + m2*16 + l4*4 + reg;
                lse_ws[(size_t)m*8 + h] = mx + __logf(s);
            }
        }
    }
}

// ---------------- Kernel 3: per-row losses + mask + total
__global__ __launch_bounds__(64) void k_loss(
    const float* __restrict__ lse_ws, const int* __restrict__ det_t,
    const int* __restrict__ cls_t, float* __restrict__ out)
{
    int m = blockIdx.x*64 + threadIdx.x;
    if (m >= M_TOT) return;
    int r = m / 7;
    const float* L = lse_ws + (size_t)m*8;
    float det_loss = L[0] - out[(size_t)m*38 + det_t[r]];
    bool mk = det_loss < 0.25f;
    out[OFF_MASK + m] = mk ? 1.f : 0.f;
    if (mk){
        const int* ct = cls_t + r*8;
        float c = (L[0] - out[(size_t)m*38 + ct[0]]) + (L[1] - out[OFF_A + (size_t)m*25 + ct[1]]);
        #pragma unroll
        for (int j=0;j<6;j++)
            c += L[2+j] - out[OFF_AD + ((size_t)j*M_TOT + m)*35 + ct[2+j]];
        atomicAdd(out + OFF_TOTAL, c);
    }
}

extern "C" void kernel_launch(void* const* d_in, const int* in_sizes, int n_in,
                              void* d_out, int out_size, void* d_ws, size_t ws_size,
                              hipStream_t stream) {
    const float* x      = (const float*)d_in[0];
    const int*   rois   = (const int*)d_in[1];
    const int*   det    = (const int*)d_in[2];
    const int*   cls    = (const int*)d_in[3];
    const float* conv_w = (const float*)d_in[4];
    const float* conv_b = (const float*)d_in[5];
    const float* w1     = (const float*)d_in[6];
    const float* b1     = (const float*)d_in[7];
    const float* w2p    = (const float*)d_in[8];
    const float* b2p    = (const float*)d_in[9];
    const float* w2a    = (const float*)d_in[10];
    const float* b2a    = (const float*)d_in[11];
    const float* w2ad   = (const float*)d_in[12];
    const float* b2ad   = (const float*)d_in[13];
    float* out = (float*)d_out;

    char* w = (char*)d_ws;
    unsigned short* flatbf = (unsigned short*)w;                    // 7,340,032 B
    unsigned short* BtW    = (unsigned short*)(w + 7340032);        // 1,048,576 B
    unsigned short* B2     = (unsigned short*)(w + 8388608);        //    98,304 B
    float*  bias2          = (float*)(w + 8486912);                 //     1,536 B
    float*  lse            = (float*)(w + 8488448);                 //   229,376 B
    float*  P              = (float*)(w + 8717824);                 // 12,546,072 B

    k_pre_cvt<<<3069 + 128 + 192, 256, 0, stream>>>(x, w1, w2p, b2p, w2a, b2a, w2ad, b2ad,
                                                    P, BtW, B2, bias2);
    k_extract<<<NROIS, 256, 0, stream>>>(P, rois, conv_w, conv_b, flatbf);
    k_fc1_heads<<<dim3(56, 8), 256, 0, stream>>>(flatbf, BtW, b1, B2, bias2, out, lse);
    k_loss<<<112, 64, 0, stream>>>(lse, det, cls, out);
}